// Round 1
// baseline (13479.897 us; speedup 1.0000x reference)
//
#include <hip/hip_runtime.h>
#include <hip/hip_bf16.h>

// Collapsed-projector persistent-GRU kernel for MI355X.
// 4 independent batch groups (M=16) x 64 column-blocks, 1 block/CU,
// register-resident weight fragments, 1 device-scope barrier per timestep.

#define HIDDEN 1024
#define INDIM  63
#define TSEQ   512
#define MB     16
#define NGRP   4
#define NBLK   64

typedef __attribute__((ext_vector_type(8))) short bfrag8;  // 8 bf16 in 4 VGPRs
typedef __attribute__((ext_vector_type(4))) float ffrag4;  // MFMA accumulator

#define MFMA_B16(a, b, c) __builtin_amdgcn_mfma_f32_16x16x32_bf16((a), (b), (c), 0, 0, 0)

__device__ __forceinline__ short f2bf(float x) {
  __hip_bfloat16 b = __float2bfloat16(x);
  return __builtin_bit_cast(short, b);
}
__device__ __forceinline__ float bf2f(short s) {
  unsigned u = ((unsigned)(unsigned short)s) << 16;
  return __builtin_bit_cast(float, u);
}

// ---------------- precompute kernels ----------------

// t1[o] = b2[o] + sum_i W2[o][i] * b1[i]   (one wave per output)
__global__ void k_t1(const float* __restrict__ W2, const float* __restrict__ b1,
                     const float* __restrict__ b2, float* __restrict__ t1) {
  const int w = threadIdx.x >> 6, lane = threadIdx.x & 63;
  const int o = blockIdx.x * 4 + w;
  if (o >= HIDDEN) return;
  const float* row = W2 + (size_t)o * HIDDEN;
  float s = 0.f;
  for (int k = lane; k < HIDDEN; k += 64) s += row[k] * b1[k];
  for (int off = 32; off; off >>= 1) s += __shfl_down(s, off, 64);
  if (lane == 0) t1[o] = s + b2[o];
}

// bp[d] = b3[d] + sum_o W3[d][o] * t1[o]
__global__ void k_bp(const float* __restrict__ W3, const float* __restrict__ t1,
                     const float* __restrict__ b3, float* __restrict__ bp) {
  const int w = threadIdx.x >> 6, lane = threadIdx.x & 63;
  for (int d = w; d < INDIM; d += 4) {
    const float* row = W3 + (size_t)d * HIDDEN;
    float s = 0.f;
    for (int k = lane; k < HIDDEN; k += 64) s += row[k] * t1[k];
    for (int off = 32; off; off >>= 1) s += __shfl_down(s, off, 64);
    if (lane == 0) bp[d] = s + b3[d];
  }
}

// C[M][N] = A[M][K] * B[K][N], fp32, simple 16x16 LDS tiles (one-time use)
__global__ void k_gemm(const float* __restrict__ A, const float* __restrict__ B,
                       float* __restrict__ C, int M, int N, int K) {
  __shared__ float As[16][17], Bs[16][17];
  const int tx = threadIdx.x, ty = threadIdx.y;
  const int row = blockIdx.y * 16 + ty;
  const int col = blockIdx.x * 16 + tx;
  float acc = 0.f;
  for (int k0 = 0; k0 < K; k0 += 16) {
    As[ty][tx] = (row < M) ? A[(size_t)row * K + k0 + tx] : 0.f;
    Bs[ty][tx] = B[(size_t)(k0 + ty) * N + col];
    __syncthreads();
#pragma unroll
    for (int kk = 0; kk < 16; ++kk) acc += As[ty][kk] * Bs[kk][tx];
    __syncthreads();
  }
  if (row < M && col < N) C[(size_t)row * N + col] = acc;
}

// ---------------- main persistent kernel ----------------

__global__ __launch_bounds__(256, 1) void k_main(
    const float* __restrict__ X,
    const float* __restrict__ W_ih, const float* __restrict__ W_hh,
    const float* __restrict__ b_ih, const float* __restrict__ b_hh,
    const float* __restrict__ WpF, const float* __restrict__ bpF,
    const int* __restrict__ pCL, const int* __restrict__ pGT,
    short* __restrict__ hb, unsigned* __restrict__ cnt,
    float* __restrict__ OUT) {
  // LDS: pads chosen so b128 row-strides are 16B-aligned and <=2-way bank aliased
  __shared__ short h_st[MB][HIDDEN + 8];   // h(t-1)/h(t) staged, stride 2064B
  __shared__ short inp_bf[MB][88];         // inp bf16, stride 176B
  __shared__ float inp_f[MB][68];          // inp fp32 (residual), stride 272B
  __shared__ float gt_z[MB][16], gt_hn[MB][16];
  __shared__ float gt_ir[MB][16], gt_iz[MB][16], gt_in[MB][16];

  const int tid = threadIdx.x;
  const int w = tid >> 6;        // wave 0..3: gates r,z,hn / gi
  const int lane = tid & 63;
  const int c = lane & 15;
  const int quad = lane >> 4;
  const int g = blockIdx.x >> 6; // batch group
  const int j = blockIdx.x & 63; // 16-col slice

  const int gtv = pGT[0];
  int period = pCL[0] + gtv;
  if (period < 1) period = 1;

  // --- persistent register-resident weight fragments ---
  bfrag8 wB[32];  // w<3: W_hh rows [w*1024 + 16j + c][*]; w==3: W_ih frags in [0..5]
  bfrag8 wp[32];  // Wp row 16w+c
  if (w < 3) {
    const float* wr = W_hh + ((size_t)w * HIDDEN + (size_t)j * 16 + c) * HIDDEN;
#pragma unroll
    for (int ks = 0; ks < 32; ++ks) {
      const float* p = wr + ks * 32 + quad * 8;
      bfrag8 f;
#pragma unroll
      for (int e = 0; e < 8; ++e) f[e] = f2bf(p[e]);
      wB[ks] = f;
    }
  } else {
#pragma unroll
    for (int gate = 0; gate < 3; ++gate) {
      const float* wr = W_ih + ((size_t)gate * HIDDEN + (size_t)j * 16 + c) * INDIM;
#pragma unroll
      for (int ks = 0; ks < 2; ++ks) {
        bfrag8 f;
#pragma unroll
        for (int e = 0; e < 8; ++e) {
          int k = ks * 32 + quad * 8 + e;
          f[e] = (k < INDIM) ? f2bf(wr[k]) : (short)0;
        }
        wB[gate * 2 + ks] = f;
      }
    }
  }
  const int dd = 16 * w + c;  // out column this lane produces
  {
    const float* wr = WpF + (size_t)dd * HIDDEN;
#pragma unroll
    for (int ks = 0; ks < 32; ++ks) {
      bfrag8 f;
#pragma unroll
      for (int e = 0; e < 8; ++e)
        f[e] = (dd < INDIM) ? f2bf(wr[ks * 32 + quad * 8 + e]) : (short)0;
      wp[ks] = f;
    }
  }

  float bias_g;
  if (w == 0)      bias_g = b_ih[j * 16 + c] + b_hh[j * 16 + c];
  else if (w == 1) bias_g = b_ih[HIDDEN + j * 16 + c] + b_hh[HIDDEN + j * 16 + c];
  else if (w == 2) bias_g = b_hh[2 * HIDDEN + j * 16 + c];
  else             bias_g = b_ih[2 * HIDDEN + j * 16 + c];
  const float bp_l = (dd < INDIM) ? bpF[dd] : 0.f;

  // zero LDS (h(-1)=0, o0=0)
  for (int i = tid; i < MB * (HIDDEN + 8); i += 256) ((short*)h_st)[i] = 0;
  for (int i = tid; i < MB * 88; i += 256) ((short*)inp_bf)[i] = 0;
  for (int i = tid; i < MB * 68; i += 256) ((float*)inp_f)[i] = 0.f;

  unsigned* cnt_g = cnt + g * 64;  // 256B apart per group
  short* hb_g[2] = {hb + (size_t)g * MB * HIDDEN,
                    hb + (size_t)(NGRP + g) * MB * HIDDEN};

  for (int t = 0; t < TSEQ; ++t) {
    const bool teach = ((t % period) < gtv);
    if (teach) {
      const int row = tid >> 4, d0 = (tid & 15) * 4;
      const float* xr = X + ((size_t)(g * MB + row) * TSEQ + t) * INDIM;
#pragma unroll
      for (int e = 0; e < 4; ++e) {
        int d = d0 + e;
        float v = (d < INDIM) ? xr[d] : 0.f;
        inp_f[row][d] = v;
        inp_bf[row][d] = f2bf(v);
      }
    }
    __syncthreads();  // inp ready; h_st holds h(t-1)

    ffrag4 ghr;  // w0's r tile, lives to epilogue
    if (w < 3) {
      ffrag4 acc[4];
#pragma unroll
      for (int e = 0; e < 4; ++e) {
        acc[0][e] = bias_g; acc[1][e] = 0.f; acc[2][e] = 0.f; acc[3][e] = 0.f;
      }
#pragma unroll
      for (int ks = 0; ks < 32; ++ks) {
        const bfrag8 a = *(const bfrag8*)&h_st[c][ks * 32 + quad * 8];
        acc[ks & 3] = MFMA_B16(a, wB[ks], acc[ks & 3]);
      }
      ffrag4 gsum = acc[0] + acc[1] + acc[2] + acc[3];
      if (w == 1) {
#pragma unroll
        for (int i = 0; i < 4; ++i) gt_z[quad * 4 + i][c] = gsum[i];
      } else if (w == 2) {
#pragma unroll
        for (int i = 0; i < 4; ++i) gt_hn[quad * 4 + i][c] = gsum[i];
      } else {
        ghr = gsum;
      }
    } else {
      ffrag4 gir, giz, gin;
#pragma unroll
      for (int e = 0; e < 4; ++e) { gir[e] = 0.f; giz[e] = 0.f; gin[e] = bias_g; }
#pragma unroll
      for (int ks = 0; ks < 2; ++ks) {
        const bfrag8 a = *(const bfrag8*)&inp_bf[c][ks * 32 + quad * 8];
        gir = MFMA_B16(a, wB[0 + ks], gir);
        giz = MFMA_B16(a, wB[2 + ks], giz);
        gin = MFMA_B16(a, wB[4 + ks], gin);
      }
#pragma unroll
      for (int i = 0; i < 4; ++i) {
        gt_ir[quad * 4 + i][c] = gir[i];
        gt_iz[quad * 4 + i][c] = giz[i];
        gt_in[quad * 4 + i][c] = gin[i];
      }
    }
    __syncthreads();  // gate tiles ready

    if (w == 0) {
      short* hw = hb_g[t & 1];
#pragma unroll
      for (int i = 0; i < 4; ++i) {
        const int row = quad * 4 + i;
        float r = 1.f / (1.f + __expf(-(ghr[i] + gt_ir[row][c])));
        float z = 1.f / (1.f + __expf(-(gt_z[row][c] + gt_iz[row][c])));
        float n = tanhf(gt_in[row][c] + r * gt_hn[row][c]);
        float hp = bf2f(h_st[row][j * 16 + c]);
        hw[(size_t)row * HIDDEN + j * 16 + c] = f2bf((1.f - z) * n + z * hp);
      }
      __threadfence();  // release h slice (device scope)
      if (lane == 0)
        __hip_atomic_fetch_add(cnt_g, 1u, __ATOMIC_RELAXED, __HIP_MEMORY_SCOPE_AGENT);
    }
    if (tid == 0) {
      const unsigned target = (unsigned)NBLK * (unsigned)(t + 1);
      while (__hip_atomic_load(cnt_g, __ATOMIC_RELAXED, __HIP_MEMORY_SCOPE_AGENT) < target)
        __builtin_amdgcn_s_sleep(1);
    }
    __syncthreads();
    __threadfence();  // acquire before reading other blocks' h slices

    {  // stage full h(t) -> LDS (coalesced 16B loads)
      const short* hr = hb_g[t & 1];
#pragma unroll
      for (int s = 0; s < 8; ++s) {
        const int seg = tid + s * 256;
        const int row = seg >> 7;
        const int kb = (seg & 127) * 8;
        *(bfrag8*)&h_st[row][kb] = *(const bfrag8*)&hr[(size_t)row * HIDDEN + kb];
      }
    }
    __syncthreads();  // h_st = h(t); also feeds next iteration's gh

    // out(t) = inp(t) + h(t) @ Wp^T + bp
    // replicated in every block only when the next step free-runs; j==0 always (global write)
    const bool rep = (t + 1 < TSEQ) && !(((t + 1) % period) < gtv);
    if (rep || j == 0) {
      ffrag4 oa0, oa1;
#pragma unroll
      for (int e = 0; e < 4; ++e) { oa0[e] = bp_l; oa1[e] = 0.f; }
#pragma unroll
      for (int ks = 0; ks < 32; ++ks) {
        const bfrag8 a = *(const bfrag8*)&h_st[c][ks * 32 + quad * 8];
        if (ks & 1) oa1 = MFMA_B16(a, wp[ks], oa1);
        else        oa0 = MFMA_B16(a, wp[ks], oa0);
      }
      ffrag4 o = oa0 + oa1;
#pragma unroll
      for (int i = 0; i < 4; ++i) {
        const int row = quad * 4 + i;
        if (dd < INDIM) {
          float val = o[i] + inp_f[row][dd];
          if (j == 0) OUT[((size_t)(g * MB + row) * TSEQ + t) * INDIM + dd] = val;
          if (rep) { inp_f[row][dd] = val; inp_bf[row][dd] = f2bf(val); }
        } else if (rep) {
          inp_bf[row][dd] = 0;  // K pad for gi must stay zero
        }
      }
    }
    // next loop-head __syncthreads orders inp writes vs MFMA reads
  }
}

// ---------------- host ----------------

extern "C" void kernel_launch(void* const* d_in, const int* in_sizes, int n_in,
                              void* d_out, int out_size, void* d_ws, size_t ws_size,
                              hipStream_t stream) {
  const float* X    = (const float*)d_in[0];
  const float* W_ih = (const float*)d_in[1];
  const float* W_hh = (const float*)d_in[2];
  const float* b_ih = (const float*)d_in[3];
  const float* b_hh = (const float*)d_in[4];
  const float* W1   = (const float*)d_in[5];
  const float* b1   = (const float*)d_in[6];
  const float* W2   = (const float*)d_in[7];
  const float* b2   = (const float*)d_in[8];
  const float* W3   = (const float*)d_in[9];
  const float* b3   = (const float*)d_in[10];
  const int* pCL    = (const int*)d_in[11];
  const int* pGT    = (const int*)d_in[12];
  float* OUT = (float*)d_out;

  char* ws = (char*)d_ws;
  unsigned* cnt = (unsigned*)ws;          // 1 KB (4 counters, 256B apart)
  float* bp = (float*)(ws + 1024);        // 63 f32
  float* t1 = (float*)(ws + 2048);        // 1024 f32
  float* T2 = (float*)(ws + 8192);        // 63x1024 f32
  float* Wp = (float*)(ws + 270336);      // 63x1024 f32
  short* hb = (short*)(ws + 532480);      // 2 x 4 x 16 x 1024 bf16
  if (ws_size < 795 * 1024) return;       // need ~776 KB of scratch

  hipMemsetAsync(cnt, 0, 1024, stream);
  k_t1<<<256, 256, 0, stream>>>(W2, b1, b2, t1);
  k_gemm<<<dim3(64, 4), dim3(16, 16), 0, stream>>>(W3, W2, T2, INDIM, HIDDEN, HIDDEN);
  k_gemm<<<dim3(64, 4), dim3(16, 16), 0, stream>>>(T2, W1, Wp, INDIM, HIDDEN, HIDDEN);
  k_bp<<<1, 256, 0, stream>>>(W3, t1, b3, bp);
  k_main<<<256, 256, 0, stream>>>(X, W_ih, W_hh, b_ih, b_hh, Wp, bp, pCL, pGT, hb, cnt, OUT);
}

// Round 2
// 5106.839 us; speedup vs baseline: 2.6396x; 2.6396x over previous
//
#include <hip/hip_runtime.h>
#include <hip/hip_bf16.h>

// Collapsed-projector persistent-GRU kernel for MI355X.
// 4 independent batch groups (M=16) x 64 column-blocks, 1 block/CU.
// Round 2: fence-free sync. h exchanged via system-scope (sc0 sc1)
// write-through stores/loads to the coherent point; per-block flags
// polled by a whole wave (no atomic RMW, no buffer_wbl2/buffer_inv).

#define HIDDEN 1024
#define INDIM  63
#define TSEQ   512
#define MB     16
#define NGRP   4
#define NBLK   64

typedef __attribute__((ext_vector_type(8))) short bfrag8;  // 8 bf16 in 4 VGPRs
typedef __attribute__((ext_vector_type(4))) float ffrag4;  // MFMA accumulator
typedef unsigned long long ull;

#define MFMA_B16(a, b, c) __builtin_amdgcn_mfma_f32_16x16x32_bf16((a), (b), (c), 0, 0, 0)

__device__ __forceinline__ short f2bf(float x) {
  __hip_bfloat16 b = __float2bfloat16(x);
  return __builtin_bit_cast(short, b);
}
__device__ __forceinline__ float bf2f(short s) {
  unsigned u = ((unsigned)(unsigned short)s) << 16;
  return __builtin_bit_cast(float, u);
}

// ---------------- precompute kernels ----------------

__global__ void k_t1(const float* __restrict__ W2, const float* __restrict__ b1,
                     const float* __restrict__ b2, float* __restrict__ t1) {
  const int w = threadIdx.x >> 6, lane = threadIdx.x & 63;
  const int o = blockIdx.x * 4 + w;
  if (o >= HIDDEN) return;
  const float* row = W2 + (size_t)o * HIDDEN;
  float s = 0.f;
  for (int k = lane; k < HIDDEN; k += 64) s += row[k] * b1[k];
  for (int off = 32; off; off >>= 1) s += __shfl_down(s, off, 64);
  if (lane == 0) t1[o] = s + b2[o];
}

__global__ void k_bp(const float* __restrict__ W3, const float* __restrict__ t1,
                     const float* __restrict__ b3, float* __restrict__ bp) {
  const int w = threadIdx.x >> 6, lane = threadIdx.x & 63;
  for (int d = w; d < INDIM; d += 4) {
    const float* row = W3 + (size_t)d * HIDDEN;
    float s = 0.f;
    for (int k = lane; k < HIDDEN; k += 64) s += row[k] * t1[k];
    for (int off = 32; off; off >>= 1) s += __shfl_down(s, off, 64);
    if (lane == 0) bp[d] = s + b3[d];
  }
}

__global__ void k_gemm(const float* __restrict__ A, const float* __restrict__ B,
                       float* __restrict__ C, int M, int N, int K) {
  __shared__ float As[16][17], Bs[16][17];
  const int tx = threadIdx.x, ty = threadIdx.y;
  const int row = blockIdx.y * 16 + ty;
  const int col = blockIdx.x * 16 + tx;
  float acc = 0.f;
  for (int k0 = 0; k0 < K; k0 += 16) {
    As[ty][tx] = (row < M) ? A[(size_t)row * K + k0 + tx] : 0.f;
    Bs[ty][tx] = B[(size_t)(k0 + ty) * N + col];
    __syncthreads();
#pragma unroll
    for (int kk = 0; kk < 16; ++kk) acc += As[ty][kk] * Bs[kk][tx];
    __syncthreads();
  }
  if (row < M && col < N) C[(size_t)row * N + col] = acc;
}

// ---------------- main persistent kernel ----------------

__global__ __launch_bounds__(256, 1) void k_main(
    const float* __restrict__ X,
    const float* __restrict__ W_ih, const float* __restrict__ W_hh,
    const float* __restrict__ b_ih, const float* __restrict__ b_hh,
    const float* __restrict__ WpF, const float* __restrict__ bpF,
    const int* __restrict__ pCL, const int* __restrict__ pGT,
    short* __restrict__ hb, int* __restrict__ flags,
    float* __restrict__ OUT) {
  __shared__ short h_st[MB][HIDDEN + 8];   // staged h, row stride 2064B
  __shared__ short inp_bf[MB][88];
  __shared__ float inp_f[MB][68];
  __shared__ float gt_z[MB][16], gt_hn[MB][16];
  __shared__ float gt_ir[MB][16], gt_iz[MB][16], gt_in[MB][16];
  __shared__ short htmp[MB][16];           // h-slice repack for coalesced store

  const int tid = threadIdx.x;
  const int w = tid >> 6;
  const int lane = tid & 63;
  const int c = lane & 15;
  const int quad = lane >> 4;
  const int g = blockIdx.x >> 6;
  const int j = blockIdx.x & 63;

  const int gtv = pGT[0];
  int period = pCL[0] + gtv;
  if (period < 1) period = 1;

  // --- persistent register-resident weight fragments ---
  bfrag8 wB[32];
  bfrag8 wp[32];
  if (w < 3) {
    const float* wr = W_hh + ((size_t)w * HIDDEN + (size_t)j * 16 + c) * HIDDEN;
#pragma unroll
    for (int ks = 0; ks < 32; ++ks) {
      const float* p = wr + ks * 32 + quad * 8;
      bfrag8 f;
#pragma unroll
      for (int e = 0; e < 8; ++e) f[e] = f2bf(p[e]);
      wB[ks] = f;
    }
  } else {
#pragma unroll
    for (int gate = 0; gate < 3; ++gate) {
      const float* wr = W_ih + ((size_t)gate * HIDDEN + (size_t)j * 16 + c) * INDIM;
#pragma unroll
      for (int ks = 0; ks < 2; ++ks) {
        bfrag8 f;
#pragma unroll
        for (int e = 0; e < 8; ++e) {
          int k = ks * 32 + quad * 8 + e;
          f[e] = (k < INDIM) ? f2bf(wr[k]) : (short)0;
        }
        wB[gate * 2 + ks] = f;
      }
    }
  }
  const int dd = 16 * w + c;
  {
    const float* wr = WpF + (size_t)dd * HIDDEN;
#pragma unroll
    for (int ks = 0; ks < 32; ++ks) {
      bfrag8 f;
#pragma unroll
      for (int e = 0; e < 8; ++e)
        f[e] = (dd < INDIM) ? f2bf(wr[ks * 32 + quad * 8 + e]) : (short)0;
      wp[ks] = f;
    }
  }

  float bias_g;
  if (w == 0)      bias_g = b_ih[j * 16 + c] + b_hh[j * 16 + c];
  else if (w == 1) bias_g = b_ih[HIDDEN + j * 16 + c] + b_hh[HIDDEN + j * 16 + c];
  else if (w == 2) bias_g = b_hh[2 * HIDDEN + j * 16 + c];
  else             bias_g = b_ih[2 * HIDDEN + j * 16 + c];
  const float bp_l = (dd < INDIM) ? bpF[dd] : 0.f;

  for (int i = tid; i < MB * (HIDDEN + 8); i += 256) ((short*)h_st)[i] = 0;
  for (int i = tid; i < MB * 88; i += 256) ((short*)inp_bf)[i] = 0;
  for (int i = tid; i < MB * 68; i += 256) ((float*)inp_f)[i] = 0.f;

  int* flg = flags + g * 64;  // this group's 64 flags (256B, contiguous)
  short* hb_g[2] = {hb + (size_t)g * MB * HIDDEN,
                    hb + (size_t)(NGRP + g) * MB * HIDDEN};

  for (int t = 0; t < TSEQ; ++t) {
    const bool teach = ((t % period) < gtv);
    if (teach) {
      const int row = tid >> 4, d0 = (tid & 15) * 4;
      const float* xr = X + ((size_t)(g * MB + row) * TSEQ + t) * INDIM;
#pragma unroll
      for (int e = 0; e < 4; ++e) {
        int d = d0 + e;
        float v = (d < INDIM) ? xr[d] : 0.f;
        inp_f[row][d] = v;
        inp_bf[row][d] = f2bf(v);
      }
    }
    __syncthreads();  // inp ready; h_st holds h(t-1)

    ffrag4 ghr;
    if (w < 3) {
      ffrag4 acc[4];
#pragma unroll
      for (int e = 0; e < 4; ++e) {
        acc[0][e] = bias_g; acc[1][e] = 0.f; acc[2][e] = 0.f; acc[3][e] = 0.f;
      }
#pragma unroll
      for (int ks = 0; ks < 32; ++ks) {
        const bfrag8 a = *(const bfrag8*)&h_st[c][ks * 32 + quad * 8];
        acc[ks & 3] = MFMA_B16(a, wB[ks], acc[ks & 3]);
      }
      ffrag4 gsum = acc[0] + acc[1] + acc[2] + acc[3];
      if (w == 1) {
#pragma unroll
        for (int i = 0; i < 4; ++i) gt_z[quad * 4 + i][c] = gsum[i];
      } else if (w == 2) {
#pragma unroll
        for (int i = 0; i < 4; ++i) gt_hn[quad * 4 + i][c] = gsum[i];
      } else {
        ghr = gsum;
      }
    } else {
      ffrag4 gir, giz, gin;
#pragma unroll
      for (int e = 0; e < 4; ++e) { gir[e] = 0.f; giz[e] = 0.f; gin[e] = bias_g; }
#pragma unroll
      for (int ks = 0; ks < 2; ++ks) {
        const bfrag8 a = *(const bfrag8*)&inp_bf[c][ks * 32 + quad * 8];
        gir = MFMA_B16(a, wB[0 + ks], gir);
        giz = MFMA_B16(a, wB[2 + ks], giz);
        gin = MFMA_B16(a, wB[4 + ks], gin);
      }
#pragma unroll
      for (int i = 0; i < 4; ++i) {
        gt_ir[quad * 4 + i][c] = gir[i];
        gt_iz[quad * 4 + i][c] = giz[i];
        gt_in[quad * 4 + i][c] = gin[i];
      }
    }
    __syncthreads();  // gate tiles ready

    if (w == 0) {
      // gates -> h_new, repack through LDS, coalesced system-scope store
#pragma unroll
      for (int i = 0; i < 4; ++i) {
        const int row = quad * 4 + i;
        float r = 1.f / (1.f + __expf(-(ghr[i] + gt_ir[row][c])));
        float z = 1.f / (1.f + __expf(-(gt_z[row][c] + gt_iz[row][c])));
        float n = tanhf(gt_in[row][c] + r * gt_hn[row][c]);
        float hp = bf2f(h_st[row][j * 16 + c]);
        htmp[row][c] = f2bf((1.f - z) * n + z * hp);
      }
      // wave-internal LDS ordering handled by compiler (lgkmcnt)
      const int srow = lane >> 2, sc4 = (lane & 3) * 4;
      ull v = *(const ull*)&htmp[srow][sc4];
      short* hw = hb_g[t & 1];
      __hip_atomic_store((ull*)&hw[(size_t)srow * HIDDEN + j * 16 + sc4], v,
                         __ATOMIC_RELAXED, __HIP_MEMORY_SCOPE_SYSTEM);
      asm volatile("s_waitcnt vmcnt(0)" ::: "memory");  // h at coherent point
      if (lane == 0)
        __hip_atomic_store(&flg[j], t + 1, __ATOMIC_RELAXED, __HIP_MEMORY_SCOPE_SYSTEM);
    }
    if (w == 1) {
      // whole wave polls all 64 flags in parallel — no RMW, no fence
      const int tgt = t + 1;
      for (;;) {
        int v = __hip_atomic_load(&flg[lane], __ATOMIC_RELAXED, __HIP_MEMORY_SCOPE_SYSTEM);
        if (__all(v >= tgt)) break;
        __builtin_amdgcn_s_sleep(1);
      }
    }
    __syncthreads();  // all waves: h(t) published by every block in group

    {  // stage full h(t) -> LDS via system-scope 8B loads (bypass stale caches)
      const ull* hr8 = (const ull*)hb_g[t & 1];
#pragma unroll
      for (int s = 0; s < 16; ++s) {
        const int seg = tid + s * 256;     // 0..4095
        const int row = seg >> 8;          // 256 ull per row
        const int u = seg & 255;
        ull v = __hip_atomic_load(&hr8[(size_t)row * (HIDDEN / 4) + u],
                                  __ATOMIC_RELAXED, __HIP_MEMORY_SCOPE_SYSTEM);
        *(ull*)&h_st[row][u * 4] = v;
      }
    }
    __syncthreads();  // h_st = h(t)

    // out(t) = inp(t) + h(t) @ Wp^T + bp
    const bool rep = (t + 1 < TSEQ) && !(((t + 1) % period) < gtv);
    if (rep || j == 0) {
      ffrag4 oa0, oa1;
#pragma unroll
      for (int e = 0; e < 4; ++e) { oa0[e] = bp_l; oa1[e] = 0.f; }
#pragma unroll
      for (int ks = 0; ks < 32; ++ks) {
        const bfrag8 a = *(const bfrag8*)&h_st[c][ks * 32 + quad * 8];
        if (ks & 1) oa1 = MFMA_B16(a, wp[ks], oa1);
        else        oa0 = MFMA_B16(a, wp[ks], oa0);
      }
      ffrag4 o = oa0 + oa1;
#pragma unroll
      for (int i = 0; i < 4; ++i) {
        const int row = quad * 4 + i;
        if (dd < INDIM) {
          float val = o[i] + inp_f[row][dd];
          if (j == 0) OUT[((size_t)(g * MB + row) * TSEQ + t) * INDIM + dd] = val;
          if (rep) { inp_f[row][dd] = val; inp_bf[row][dd] = f2bf(val); }
        } else if (rep) {
          inp_bf[row][dd] = 0;
        }
      }
    }
  }
}

// ---------------- host ----------------

extern "C" void kernel_launch(void* const* d_in, const int* in_sizes, int n_in,
                              void* d_out, int out_size, void* d_ws, size_t ws_size,
                              hipStream_t stream) {
  const float* X    = (const float*)d_in[0];
  const float* W_ih = (const float*)d_in[1];
  const float* W_hh = (const float*)d_in[2];
  const float* b_ih = (const float*)d_in[3];
  const float* b_hh = (const float*)d_in[4];
  const float* W1   = (const float*)d_in[5];
  const float* b1   = (const float*)d_in[6];
  const float* W2   = (const float*)d_in[7];
  const float* b2   = (const float*)d_in[8];
  const float* W3   = (const float*)d_in[9];
  const float* b3   = (const float*)d_in[10];
  const int* pCL    = (const int*)d_in[11];
  const int* pGT    = (const int*)d_in[12];
  float* OUT = (float*)d_out;

  char* ws = (char*)d_ws;
  int* flags = (int*)ws;                  // 4 groups x 64 flags (1 KB)
  float* bp = (float*)(ws + 1024);        // 63 f32
  float* t1 = (float*)(ws + 2048);        // 1024 f32
  float* T2 = (float*)(ws + 8192);        // 63x1024 f32
  float* Wp = (float*)(ws + 270336);      // 63x1024 f32
  short* hb = (short*)(ws + 532480);      // 2 x 4 x 16 x 1024 bf16
  if (ws_size < 795 * 1024) return;

  hipMemsetAsync(flags, 0, 1024, stream);
  k_t1<<<256, 256, 0, stream>>>(W2, b1, b2, t1);
  k_gemm<<<dim3(64, 4), dim3(16, 16), 0, stream>>>(W3, W2, T2, INDIM, HIDDEN, HIDDEN);
  k_gemm<<<dim3(64, 4), dim3(16, 16), 0, stream>>>(T2, W1, Wp, INDIM, HIDDEN, HIDDEN);
  k_bp<<<1, 256, 0, stream>>>(W3, t1, b3, bp);
  k_main<<<256, 256, 0, stream>>>(X, W_ih, W_hh, b_ih, b_hh, Wp, bp, pCL, pGT, hb, flags, OUT);
}

// Round 4
// 3813.104 us; speedup vs baseline: 3.5352x; 1.3393x over previous
//
#include <hip/hip_runtime.h>
#include <hip/hip_bf16.h>

// Collapsed-projector persistent-GRU kernel for MI355X.
// 4 independent batch groups (M=16) x 64 column-blocks, 1 block/CU.
// Round 4: tag-in-data sync (gather IS the barrier) + TBAA-safe repack.
// h exchanged as 8B words = 2 bf16 + 32-bit step tag at system scope.

#define HIDDEN 1024
#define INDIM  63
#define TSEQ   512
#define MB     16
#define NGRP   4
#define NBLK   64
#define HWORDS 512          // 8B words per h row (2 cols each)

typedef __attribute__((ext_vector_type(8))) short bfrag8;  // 8 bf16 in 4 VGPRs
typedef __attribute__((ext_vector_type(4))) float ffrag4;  // MFMA accumulator
typedef unsigned long long ull;

#define MFMA_B16(a, b, c) __builtin_amdgcn_mfma_f32_16x16x32_bf16((a), (b), (c), 0, 0, 0)

__device__ __forceinline__ short f2bf(float x) {
  __hip_bfloat16 b = __float2bfloat16(x);
  return __builtin_bit_cast(short, b);
}
__device__ __forceinline__ float bf2f(short s) {
  unsigned u = ((unsigned)(unsigned short)s) << 16;
  return __builtin_bit_cast(float, u);
}

// ---------------- precompute kernels ----------------

__global__ void k_t1(const float* __restrict__ W2, const float* __restrict__ b1,
                     const float* __restrict__ b2, float* __restrict__ t1) {
  const int w = threadIdx.x >> 6, lane = threadIdx.x & 63;
  const int o = blockIdx.x * 4 + w;
  if (o >= HIDDEN) return;
  const float* row = W2 + (size_t)o * HIDDEN;
  float s = 0.f;
  for (int k = lane; k < HIDDEN; k += 64) s += row[k] * b1[k];
  for (int off = 32; off; off >>= 1) s += __shfl_down(s, off, 64);
  if (lane == 0) t1[o] = s + b2[o];
}

__global__ void k_bp(const float* __restrict__ W3, const float* __restrict__ t1,
                     const float* __restrict__ b3, float* __restrict__ bp) {
  const int w = threadIdx.x >> 6, lane = threadIdx.x & 63;
  for (int d = w; d < INDIM; d += 4) {
    const float* row = W3 + (size_t)d * HIDDEN;
    float s = 0.f;
    for (int k = lane; k < HIDDEN; k += 64) s += row[k] * t1[k];
    for (int off = 32; off; off >>= 1) s += __shfl_down(s, off, 64);
    if (lane == 0) bp[d] = s + b3[d];
  }
}

__global__ void k_gemm(const float* __restrict__ A, const float* __restrict__ B,
                       float* __restrict__ C, int M, int N, int K) {
  __shared__ float As[16][17], Bs[16][17];
  const int tx = threadIdx.x, ty = threadIdx.y;
  const int row = blockIdx.y * 16 + ty;
  const int col = blockIdx.x * 16 + tx;
  float acc = 0.f;
  for (int k0 = 0; k0 < K; k0 += 16) {
    As[ty][tx] = (row < M) ? A[(size_t)row * K + k0 + tx] : 0.f;
    Bs[ty][tx] = B[(size_t)(k0 + ty) * N + col];
    __syncthreads();
#pragma unroll
    for (int kk = 0; kk < 16; ++kk) acc += As[ty][kk] * Bs[kk][tx];
    __syncthreads();
  }
  if (row < M && col < N) C[(size_t)row * N + col] = acc;
}

// ---------------- main persistent kernel ----------------

__global__ __launch_bounds__(256, 1) void k_main(
    const float* __restrict__ X,
    const float* __restrict__ W_ih, const float* __restrict__ W_hh,
    const float* __restrict__ b_ih, const float* __restrict__ b_hh,
    const float* __restrict__ WpF, const float* __restrict__ bpF,
    const int* __restrict__ pCL, const int* __restrict__ pGT,
    ull* __restrict__ hb, float* __restrict__ OUT) {
  __shared__ short h_st[MB][HIDDEN + 8];   // staged h, row stride 2064B
  __shared__ short inp_bf[MB][88];
  __shared__ float inp_f[MB][68];
  __shared__ float gt_z[MB][16], gt_hn[MB][16];
  __shared__ float gt_ir[MB][16], gt_iz[MB][16], gt_in[MB][16];
  __shared__ short htmp[MB][16];           // h-slice repack for packed store

  const int tid = threadIdx.x;
  const int w = tid >> 6;
  const int lane = tid & 63;
  const int c = lane & 15;
  const int quad = lane >> 4;
  const int g = blockIdx.x >> 6;
  const int j = blockIdx.x & 63;

  const int gtv = pGT[0];
  int period = pCL[0] + gtv;
  if (period < 1) period = 1;

  // --- persistent register-resident weight fragments ---
  bfrag8 wB[32];
  bfrag8 wp[32];
  if (w < 3) {
    const float* wr = W_hh + ((size_t)w * HIDDEN + (size_t)j * 16 + c) * HIDDEN;
#pragma unroll
    for (int ks = 0; ks < 32; ++ks) {
      const float* p = wr + ks * 32 + quad * 8;
      bfrag8 f;
#pragma unroll
      for (int e = 0; e < 8; ++e) f[e] = f2bf(p[e]);
      wB[ks] = f;
    }
  } else {
#pragma unroll
    for (int gate = 0; gate < 3; ++gate) {
      const float* wr = W_ih + ((size_t)gate * HIDDEN + (size_t)j * 16 + c) * INDIM;
#pragma unroll
      for (int ks = 0; ks < 2; ++ks) {
        bfrag8 f;
#pragma unroll
        for (int e = 0; e < 8; ++e) {
          int k = ks * 32 + quad * 8 + e;
          f[e] = (k < INDIM) ? f2bf(wr[k]) : (short)0;
        }
        wB[gate * 2 + ks] = f;
      }
    }
  }
  const int dd = 16 * w + c;
  {
    const float* wr = WpF + (size_t)dd * HIDDEN;
#pragma unroll
    for (int ks = 0; ks < 32; ++ks) {
      bfrag8 f;
#pragma unroll
      for (int e = 0; e < 8; ++e)
        f[e] = (dd < INDIM) ? f2bf(wr[ks * 32 + quad * 8 + e]) : (short)0;
      wp[ks] = f;
    }
  }

  float bias_g;
  if (w == 0)      bias_g = b_ih[j * 16 + c] + b_hh[j * 16 + c];
  else if (w == 1) bias_g = b_ih[HIDDEN + j * 16 + c] + b_hh[HIDDEN + j * 16 + c];
  else if (w == 2) bias_g = b_hh[2 * HIDDEN + j * 16 + c];
  else             bias_g = b_ih[2 * HIDDEN + j * 16 + c];
  const float bp_l = (dd < INDIM) ? bpF[dd] : 0.f;

  for (int i = tid; i < MB * (HIDDEN + 8); i += 256) ((short*)h_st)[i] = 0;
  for (int i = tid; i < MB * 88; i += 256) ((short*)inp_bf)[i] = 0;
  for (int i = tid; i < MB * 68; i += 256) ((float*)inp_f)[i] = 0.f;

  // tagged h buffers: [2][NGRP][MB][HWORDS] ull
  ull* hb_g[2] = {hb + (size_t)g * MB * HWORDS,
                  hb + (size_t)(NGRP + g) * MB * HWORDS};

  for (int t = 0; t < TSEQ; ++t) {
    const unsigned tg = (unsigned)(t + 1);
    const bool teach = ((t % period) < gtv);
    if (teach) {
      const int row = tid >> 4, d0 = (tid & 15) * 4;
      const float* xr = X + ((size_t)(g * MB + row) * TSEQ + t) * INDIM;
#pragma unroll
      for (int e = 0; e < 4; ++e) {
        int d = d0 + e;
        float v = (d < INDIM) ? xr[d] : 0.f;
        inp_f[row][d] = v;
        inp_bf[row][d] = f2bf(v);
      }
    }
    __syncthreads();  // S1: inp ready; h_st holds h(t-1)

    ffrag4 ghr;
    float hp[4];  // w0 snapshots h_prev before gather overwrites h_st
    if (w < 3) {
      ffrag4 acc[4];
#pragma unroll
      for (int e = 0; e < 4; ++e) {
        acc[0][e] = bias_g; acc[1][e] = 0.f; acc[2][e] = 0.f; acc[3][e] = 0.f;
      }
#pragma unroll
      for (int ks = 0; ks < 32; ++ks) {
        const bfrag8 a = *(const bfrag8*)&h_st[c][ks * 32 + quad * 8];
        acc[ks & 3] = MFMA_B16(a, wB[ks], acc[ks & 3]);
      }
      ffrag4 gsum = acc[0] + acc[1] + acc[2] + acc[3];
      if (w == 1) {
#pragma unroll
        for (int i = 0; i < 4; ++i) gt_z[quad * 4 + i][c] = gsum[i];
      } else if (w == 2) {
#pragma unroll
        for (int i = 0; i < 4; ++i) gt_hn[quad * 4 + i][c] = gsum[i];
      } else {
        ghr = gsum;
#pragma unroll
        for (int i = 0; i < 4; ++i) hp[i] = bf2f(h_st[quad * 4 + i][j * 16 + c]);
      }
    } else {
      ffrag4 gir, giz, gin;
#pragma unroll
      for (int e = 0; e < 4; ++e) { gir[e] = 0.f; giz[e] = 0.f; gin[e] = bias_g; }
#pragma unroll
      for (int ks = 0; ks < 2; ++ks) {
        const bfrag8 a = *(const bfrag8*)&inp_bf[c][ks * 32 + quad * 8];
        gir = MFMA_B16(a, wB[0 + ks], gir);
        giz = MFMA_B16(a, wB[2 + ks], giz);
        gin = MFMA_B16(a, wB[4 + ks], gin);
      }
#pragma unroll
      for (int i = 0; i < 4; ++i) {
        gt_ir[quad * 4 + i][c] = gir[i];
        gt_iz[quad * 4 + i][c] = giz[i];
        gt_in[quad * 4 + i][c] = gin[i];
      }
    }
    __syncthreads();  // S2: gate tiles ready; h_st now dead until gather refill

    ull* hw = hb_g[t & 1];
    if (w == 0) {
      // gates -> h_new (bf16) -> htmp (wave-local repack) -> tagged publish
#pragma unroll
      for (int i = 0; i < 4; ++i) {
        const int row = quad * 4 + i;
        float r = 1.f / (1.f + __expf(-(ghr[i] + gt_ir[row][c])));
        float z = 1.f / (1.f + __expf(-(gt_z[row][c] + gt_iz[row][c])));
        float n = tanhf(gt_in[row][c] + r * gt_hn[row][c]);
        htmp[row][c] = f2bf((1.f - z) * n + z * hp[i]);
      }
      // TBAA-safe repack: same-typed (short) loads + compiler memory fence so
      // the reads can never be scheduled above the htmp stores.
      asm volatile("" ::: "memory");
      const int r = lane >> 2, q4 = (lane & 3) * 4;   // 4 cols = 2 words per lane
      unsigned lo0 = (unsigned)(unsigned short)htmp[r][q4 + 0] |
                     ((unsigned)(unsigned short)htmp[r][q4 + 1] << 16);
      unsigned lo1 = (unsigned)(unsigned short)htmp[r][q4 + 2] |
                     ((unsigned)(unsigned short)htmp[r][q4 + 3] << 16);
      ull w0v = ((ull)tg << 32) | lo0;
      ull w1v = ((ull)tg << 32) | lo1;
      ull* dst = hw + (size_t)r * HWORDS + 8 * j + (lane & 3) * 2;
      __hip_atomic_store(dst, w0v, __ATOMIC_RELAXED, __HIP_MEMORY_SCOPE_SYSTEM);
      __hip_atomic_store(dst + 1, w1v, __ATOMIC_RELAXED, __HIP_MEMORY_SCOPE_SYSTEM);
    }

    // gather h(t): the load IS the barrier — retry words until tag == t+1
    {
      ull v[32];
#pragma unroll
      for (int s = 0; s < 32; ++s)
        v[s] = __hip_atomic_load(&hw[tid + s * 256], __ATOMIC_RELAXED,
                                 __HIP_MEMORY_SCOPE_SYSTEM);
      bool bad = true;
      while (bad) {
        bad = false;
#pragma unroll
        for (int s = 0; s < 32; ++s) {
          if ((unsigned)(v[s] >> 32) != tg) {
            v[s] = __hip_atomic_load(&hw[tid + s * 256], __ATOMIC_RELAXED,
                                     __HIP_MEMORY_SCOPE_SYSTEM);
            bad = true;
          }
        }
      }
#pragma unroll
      for (int s = 0; s < 32; ++s) {
        const int widx = tid + s * 256;          // 16 rows x 512 words
        *(unsigned*)&h_st[widx >> 9][(widx & 511) * 2] = (unsigned)v[s];
      }
    }
    __syncthreads();  // S3: h_st = h(t)

    // out(t) = inp(t) + h(t) @ Wp^T + bp
    const bool rep = (t + 1 < TSEQ) && !(((t + 1) % period) < gtv);
    if (rep || j == 0) {
      ffrag4 oa0, oa1;
#pragma unroll
      for (int e = 0; e < 4; ++e) { oa0[e] = bp_l; oa1[e] = 0.f; }
#pragma unroll
      for (int ks = 0; ks < 32; ++ks) {
        const bfrag8 a = *(const bfrag8*)&h_st[c][ks * 32 + quad * 8];
        if (ks & 1) oa1 = MFMA_B16(a, wp[ks], oa1);
        else        oa0 = MFMA_B16(a, wp[ks], oa0);
      }
      ffrag4 o = oa0 + oa1;
#pragma unroll
      for (int i = 0; i < 4; ++i) {
        const int row = quad * 4 + i;
        if (dd < INDIM) {
          float val = o[i] + inp_f[row][dd];
          if (j == 0) OUT[((size_t)(g * MB + row) * TSEQ + t) * INDIM + dd] = val;
          if (rep) { inp_f[row][dd] = val; inp_bf[row][dd] = f2bf(val); }
        } else if (rep) {
          inp_bf[row][dd] = 0;
        }
      }
    }
    // loop-head S1 orders inp writes vs next gi reads
  }
}

// ---------------- host ----------------

extern "C" void kernel_launch(void* const* d_in, const int* in_sizes, int n_in,
                              void* d_out, int out_size, void* d_ws, size_t ws_size,
                              hipStream_t stream) {
  const float* X    = (const float*)d_in[0];
  const float* W_ih = (const float*)d_in[1];
  const float* W_hh = (const float*)d_in[2];
  const float* b_ih = (const float*)d_in[3];
  const float* b_hh = (const float*)d_in[4];
  const float* W1   = (const float*)d_in[5];
  const float* b1   = (const float*)d_in[6];
  const float* W2   = (const float*)d_in[7];
  const float* b2   = (const float*)d_in[8];
  const float* W3   = (const float*)d_in[9];
  const float* b3   = (const float*)d_in[10];
  const int* pCL    = (const int*)d_in[11];
  const int* pGT    = (const int*)d_in[12];
  float* OUT = (float*)d_out;

  // layout (fits in 795 KB): T2 aliases hb (dead before k_main; hb memset after)
  char* ws = (char*)d_ws;
  float* bp = (float*)(ws + 1024);        // 63 f32
  float* t1 = (float*)(ws + 2048);        // 1024 f32
  float* Wp = (float*)(ws + 8192);        // 63x1024 f32 (258048 B)
  float* T2 = (float*)(ws + 270336);      // 63x1024 f32 scratch (aliases hb)
  ull*   hb = (ull*)(ws + 270336);        // 2 x 4 x 16 x 512 ull = 512 KB
  if (ws_size < 795 * 1024) return;

  k_t1<<<256, 256, 0, stream>>>(W2, b1, b2, t1);
  k_gemm<<<dim3(64, 4), dim3(16, 16), 0, stream>>>(W3, W2, T2, INDIM, HIDDEN, HIDDEN);
  k_gemm<<<dim3(64, 4), dim3(16, 16), 0, stream>>>(T2, W1, Wp, INDIM, HIDDEN, HIDDEN);
  k_bp<<<1, 256, 0, stream>>>(W3, t1, b3, bp);
  hipMemsetAsync(hb, 0, 2 * NGRP * MB * HWORDS * sizeof(ull), stream);  // tags := 0
  k_main<<<256, 256, 0, stream>>>(X, W_ih, W_hh, b_ih, b_hh, Wp, bp, pCL, pGT, hb, OUT);
}